// Round 13
// baseline (78.137 us; speedup 1.0000x reference)
//
#include <hip/hip_runtime.h>
#include <math.h>

// ConvCapsule R13 = R12 restructured to 4 pixels / 1024 threads / 16 waves.
// Per-thread routing state IDENTICAL to R7-R12 (one (pixel,o,ig), v[4][8]).
// Weight L2 traffic halves (2048 blocks x 114KB = 235MB); staging 40 taps/4px;
// pos decode becomes shifts (xl in [0,8)). LDS = 65536 B exactly:
//   patch   [0,24576): [32 i][48 slots][16B], slot = pos ^ (i&15), stride 768
//   vtr     [24576,65536): per-wave [32 rows][80 B], chunk-rotated
//   routing [0,37888) overlay after B1: logits q*4736 ; route 18944+q*4736
// 2 blocks/CU x 16 waves = same 32-wave/CU cap as R12.

using short8 = __attribute__((ext_vector_type(8))) short;
using f32x4  = __attribute__((ext_vector_type(4))) float;

__device__ __forceinline__ unsigned short f2bf(float f) {
    unsigned u = __float_as_uint(f);
    return (unsigned short)((u + 0x7fffu + ((u >> 16) & 1u)) >> 16);  // RNE
}

template<int CTRL>
__device__ __forceinline__ float dpp_movf(float x) {
    return __int_as_float(__builtin_amdgcn_update_dpp(
        0, __float_as_int(x), CTRL, 0xF, 0xF, true));
}
__device__ __forceinline__ float swz_xor4(float x) {   // lane ^= 4
    return __int_as_float(__builtin_amdgcn_ds_swizzle(__float_as_int(x), 0x101F));
}
__device__ __forceinline__ float sum8(float x) {
    x += dpp_movf<0xB1>(x);
    x += dpp_movf<0x4E>(x);
    x += dpp_movf<0x141>(x);
    return x;
}
__device__ __forceinline__ float max8(float x) {
    x = fmaxf(x, dpp_movf<0xB1>(x));
    x = fmaxf(x, dpp_movf<0x4E>(x));
    x = fmaxf(x, dpp_movf<0x141>(x));
    return x;
}
// butterfly reduce-transpose over 8-lane group: p[j] holds partial for a=ig^j;
// returns full sum for a=ig.
__device__ __forceinline__ float reduce_xpose8(float p[8]) {
    p[0] += dpp_movf<0xB1>(p[1]);
    p[2] += dpp_movf<0xB1>(p[3]);
    p[4] += dpp_movf<0xB1>(p[5]);
    p[6] += dpp_movf<0xB1>(p[7]);
    p[0] += dpp_movf<0x4E>(p[2]);
    p[4] += dpp_movf<0x4E>(p[6]);
    p[0] += swz_xor4(p[4]);
    return p[0];
}

// ---------- merged prep: blocks [0,224) -> W bf16 repack; [224,480) -> x transpose ----------
__global__ __launch_bounds__(256)
void prep(const float* __restrict__ cw, const float* __restrict__ x,
          unsigned short* __restrict__ wp, unsigned short* __restrict__ xt) {
    __shared__ unsigned short tile[32 * 256];
    const int t = threadIdx.x;
    if (blockIdx.x < 224) {
        // W -> bf16, [s(7)][g(4)][oa(256)][j(8)], k = s*32+g*8+j
        const int idx = blockIdx.x * 256 + t;         // 57344 total
        const int j  = idx & 7;
        const int oa = (idx >> 3) & 255;
        const int g  = (idx >> 11) & 3;
        const int s  = idx >> 13;
        const int k  = s * 32 + g * 8 + j;
        wp[idx] = (k < 200) ? f2bf(cw[k * 256 + oa]) : (unsigned short)0;
        return;
    }
    // x -> bf16 transposed [b][y][x][i*8+ci]
    const int bid = blockIdx.x - 224;                 // 256 blocks
    const int b = bid >> 5, y = bid & 31;
    const float* src = x + (((size_t)((b << 8) + t)) << 10) + (y << 5);
    #pragma unroll
    for (int c = 0; c < 8; ++c) {
        float4 v = *(const float4*)(src + c * 4);
        tile[(c * 4 + 0) * 256 + t] = f2bf(v.x);
        tile[(c * 4 + 1) * 256 + t] = f2bf(v.y);
        tile[(c * 4 + 2) * 256 + t] = f2bf(v.z);
        tile[(c * 4 + 3) * 256 + t] = f2bf(v.w);
    }
    __syncthreads();
    unsigned short* dst = xt + ((size_t)bid << 13);
    #pragma unroll
    for (int c = 0; c < 4; ++c) {
        const int chunk = t + c * 256;
        *(short8*)(dst + chunk * 8) = *(const short8*)(&tile[chunk * 8]);
    }
}

// ---------- main fused kernel: 4 pixels / 1024 threads / 16 waves ----------
__global__ __launch_bounds__(1024, 4)
void capsule_mfma4(const unsigned short* __restrict__ xt,
                   const unsigned short* __restrict__ wp,
                   const float* __restrict__ conv_b,
                   const float* __restrict__ biases,
                   float* __restrict__ out)
{
    __shared__ __align__(16) char lds[65536];

    const int t   = threadIdx.x;
    const int blk = blockIdx.x;           // 2048
    const int b   = blk >> 8;
    const int rem = blk & 255;
    const int h   = rem >> 3;
    const int w0  = (rem & 7) << 2;       // pixels w0..w0+3

    // ---- stage patch: 40 pos (5 ky x 8 xl) x 32 i units, 16B each ----
    for (int u = t; u < 1280; u += 1024) {
        const int i = u & 31, pos = u >> 5;          // pos in [0,40)
        const int ky = pos >> 3, xl = pos & 7;
        const int y = h + ky - 2, xx = w0 + xl - 2;
        short8 vv = {0, 0, 0, 0, 0, 0, 0, 0};
        if ((unsigned)y < 32u && (unsigned)xx < 32u)
            vv = *(const short8*)(xt + (((size_t)(((b << 5) + y) << 5) + xx) << 8) + i * 8);
        *(short8*)(lds + i * 768 + ((pos ^ (i & 15)) << 4)) = vv;
    }

    const int l  = t & 63, wv = t >> 6;   // 16 waves
    const int lm = l & 15, lg = l >> 4;   // conv C-layout coords
    const int o_l = l >> 3, ig = l & 7;   // routing coords
    const int o  = ((wv & 3) << 3) + o_l; // capsule 0..31
    const int q  = wv >> 2;               // pixel 0..3

    const float cb_own   = conv_b[t & 255];
    const float bias_own = biases[t & 255];

    // W s=0 prefetch (hides L2 latency under the staging barrier)
    const unsigned short* wbase = wp + lg * 2048 + ((((wv & 3) << 6) + lm) << 3);
    short8 a0[4];
    #pragma unroll
    for (int mt = 0; mt < 4; ++mt)
        a0[mt] = *(const short8*)(wbase + mt * 128);

    f32x4 acc[4][2];
    #pragma unroll
    for (int mt = 0; mt < 4; ++mt)
        #pragma unroll
        for (int ti = 0; ti < 2; ++ti)
            acc[mt][ti] = (f32x4){0.f, 0.f, 0.f, 0.f};

    __syncthreads();   // B0: patch ready

    // conv: M=oa (A=W, wave owns 64 oa), N=i (B=patch), K=224
    #pragma unroll
    for (int s = 0; s < 7; ++s) {
        short8 a[4];
        #pragma unroll
        for (int mt = 0; mt < 4; ++mt)
            a[mt] = (s == 0) ? a0[mt]
                             : *(const short8*)(wbase + s * 8192 + mt * 128);
        const int kt = s * 4 + lg;
        int pos = 0;
        if (kt <= 24) { const int ky = kt / 5; pos = (ky << 3) + (kt - ky * 5); }
        const int pr = pos + q;           // logical slot; phys = pr ^ (i&15)
        const short8 b0 = *(const short8*)(lds + lm * 768 + ((pr ^ lm) << 4));
        const short8 b1 = *(const short8*)(lds + (16 + lm) * 768 + ((pr ^ lm) << 4));
        __builtin_amdgcn_s_setprio(1);
        #pragma unroll
        for (int mt = 0; mt < 4; ++mt) {
            acc[mt][0] = __builtin_amdgcn_mfma_f32_16x16x32_bf16(a[mt], b0, acc[mt][0], 0, 0, 0);
            acc[mt][1] = __builtin_amdgcn_mfma_f32_16x16x32_bf16(a[mt], b1, acc[mt][1], 0, 0, 0);
        }
        __builtin_amdgcn_s_setprio(0);
    }

    // ---- per-wave transpose, 4 rounds (mh,ro); vtr region dedicated ----
    // Hoisted addressing (thread-constant bases, immediate r*80 offsets):
    //   m2=0 rows 4lg+r   : chunk0 = ((lm>>2)+(lg>>1))&3
    //   m2=1 rows 16+4lg+r: chunk  = chunk0^2
    float v[4][8];                        // v[di][j]: i = 4ig+di, a = ig^j
    char* vtrb = lds + 24576 + wv * 2560; // [32 rows][80 B]
    const int chunk0 = ((lm >> 2) + (lg >> 1)) & 3;
    char* wb0 = vtrb + (lg << 2) * 80 + (chunk0 << 4) + ((lm & 3) << 2);
    char* wb1 = vtrb + (16 + (lg << 2)) * 80 + ((chunk0 ^ 2) << 4) + ((lm & 3) << 2);
    const char* rb = vtrb + ((o_l & 3) << 3) * 80 + ((((ig & 3) + (o_l & 3)) & 3) << 4);
    #pragma unroll
    for (int mh = 0; mh < 2; ++mh)
        #pragma unroll
        for (int ro = 0; ro < 2; ++ro) {
            #pragma unroll
            for (int r = 0; r < 4; ++r) {
                *(float*)(wb0 + r * 80) = acc[mh * 2 + 0][ro][r];
                *(float*)(wb1 + r * 80) = acc[mh * 2 + 1][ro][r];
            }
            if ((ig >> 2) == ro && (o_l >> 2) == mh) {
                #pragma unroll
                for (int j = 0; j < 8; ++j) {
                    const f32x4 r4 = *(const f32x4*)(rb + (ig ^ j) * 80);
                    v[0][j] = r4[0]; v[1][j] = r4[1]; v[2][j] = r4[2]; v[3][j] = r4[3];
                }
            }
        }

    // routing arrays: [32 i][37] f32 each, stride 148 B (2-way max banks)
    float* logits_q = (float*)(lds + q * 4736);
    float* route_q  = (float*)(lds + 18944 + q * 4736);
    const int rw_byte = ig * 592 + o * 4;                // [i=4ig+di][o], +di*148
    const int sm_byte = o * 148 + (ig << 4);             // row i=o, cols 4ig.., b128

    float lacc[4] = {0.f, 0.f, 0.f, 0.f};
    float actv = 0.f;

    #pragma unroll
    for (int it = 0; it < 3; ++it) {
        // ---- preact: pre(o, a=ig) ----
        float pre;
        if (it == 0) {
            float p[8];
            #pragma unroll
            for (int j = 0; j < 8; ++j)
                p[j] = (v[0][j] + v[1][j]) + (v[2][j] + v[3][j]);
            const float R = reduce_xpose8(p);
            pre = fmaf(fmaf(cb_own, 32.f, R), 1.f / 33.f, bias_own);
        } else {
            float r4[4];
            #pragma unroll
            for (int di = 0; di < 4; ++di)
                r4[di] = *(const float*)((char*)route_q + rw_byte + di * 148);
            float p[8];
            #pragma unroll
            for (int j = 0; j < 8; ++j) {
                float s = v[0][j] * r4[0];
                s = fmaf(v[1][j], r4[1], s);
                s = fmaf(v[2][j], r4[2], s);
                s = fmaf(v[3][j], r4[3], s);
                p[j] = s;
            }
            const float S_o = sum8((r4[0] + r4[1]) + (r4[2] + r4[3]));
            const float P = reduce_xpose8(p);
            pre = fmaf(cb_own, S_o, P) + bias_own;
        }

        // ---- squash over atoms ----
        const float ns = sum8(pre * pre);
        actv = pre * ns * __builtin_amdgcn_rsqf(ns) * __builtin_amdgcn_rcpf(1.f + ns);

        if (it < 2) {
            // act allgather in xor-slot order
            float ag[8];
            ag[0] = actv;
            ag[4] = swz_xor4(ag[0]);
            ag[2] = dpp_movf<0x4E>(ag[0]);
            ag[6] = dpp_movf<0x4E>(ag[4]);
            ag[1] = dpp_movf<0xB1>(ag[0]);
            ag[3] = dpp_movf<0xB1>(ag[2]);
            ag[5] = dpp_movf<0xB1>(ag[4]);
            ag[7] = dpp_movf<0xB1>(ag[6]);
            const float cbact = sum8(cb_own * actv);

            // logit update in registers
            #pragma unroll
            for (int di = 0; di < 4; ++di) {
                float d = cbact;
                #pragma unroll
                for (int j = 0; j < 8; ++j)
                    d = fmaf(v[di][j], ag[j], d);
                lacc[di] += d;
            }

            // B1 (iter0 only): all conv-patch and vtr reads complete before
            // the routing overlay reuses [0,37888)
            if (it == 0) __syncthreads();

            #pragma unroll
            for (int di = 0; di < 4; ++di)
                *(float*)((char*)logits_q + rw_byte + di * 148) = lacc[di];
            __syncthreads();   // B2/B4

            // leaky softmax over o for row i = o
            f32x4 e = *(const f32x4*)((char*)logits_q + sm_byte);
            float mx = fmaxf(fmaxf(e[0], e[1]), fmaxf(e[2], e[3]));
            mx = max8(fmaxf(mx, 0.f));                   // include leak logit 0
            e[0] = __expf(e[0] - mx); e[1] = __expf(e[1] - mx);
            e[2] = __expf(e[2] - mx); e[3] = __expf(e[3] - mx);
            const float ssum = sum8((e[0] + e[1]) + (e[2] + e[3])) + __expf(-mx);
            const float inv = __builtin_amdgcn_rcpf(ssum);
            e[0] *= inv; e[1] *= inv; e[2] *= inv; e[3] *= inv;
            *(f32x4*)((char*)route_q + sm_byte) = e;
            __syncthreads();   // B3/B5
        }
    }

    // out[b][o][h][w][a]: a = ig
    const int pix = (h << 5) + w0 + q;
    out[(((size_t)(((b << 5) + o) << 10) + pix) << 3) + ig] = actv;
}

extern "C" void kernel_launch(void* const* d_in, const int* in_sizes, int n_in,
                              void* d_out, int out_size, void* d_ws, size_t ws_size,
                              hipStream_t stream) {
    const float* x      = (const float*)d_in[0];
    const float* conv_w = (const float*)d_in[1];
    const float* conv_b = (const float*)d_in[2];
    const float* biases = (const float*)d_in[3];
    unsigned short* wp = (unsigned short*)d_ws;                     // 114,688 B
    unsigned short* xt = (unsigned short*)((char*)d_ws + 131072);   // 4 MB
    prep<<<dim3(480), dim3(256), 0, stream>>>(conv_w, x, wp, xt);
    capsule_mfma4<<<dim3(2048), dim3(1024), 0, stream>>>(xt, wp, conv_b, biases, (float*)d_out);
}

// Round 14
// 63.247 us; speedup vs baseline: 1.2354x; 1.2354x over previous
//
#include <hip/hip_runtime.h>
#include <math.h>

// ConvCapsule R14 = R12 verbatim (revert of R13's 4-pixel regression).
// Best-known configuration: 2 pixels / 512 threads / 8 waves, 4 blocks/CU.
// Ladder: 641 (fp32 VALU) -> 186 (bf16 MFMA conv) -> 83 (reg-resident routing)
// -> 77 (barrier diet) -> 63 (xor-slot routing layout + swizzles + hoisting).
// Design rules learned: barrier-synced unit <= 8 waves; >= 4 blocks/CU for
// skew absorption (R5/R13 regressions); occupancy via LDS shaping, never
// launch_bounds VGPR caps (R6); per-thread routing state = 1 vote row (R4).

using short8 = __attribute__((ext_vector_type(8))) short;
using f32x4  = __attribute__((ext_vector_type(4))) float;

__device__ __forceinline__ unsigned short f2bf(float f) {
    unsigned u = __float_as_uint(f);
    return (unsigned short)((u + 0x7fffu + ((u >> 16) & 1u)) >> 16);  // RNE
}

template<int CTRL>
__device__ __forceinline__ float dpp_movf(float x) {
    return __int_as_float(__builtin_amdgcn_update_dpp(
        0, __float_as_int(x), CTRL, 0xF, 0xF, true));
}
__device__ __forceinline__ float swz_xor4(float x) {   // lane ^= 4
    return __int_as_float(__builtin_amdgcn_ds_swizzle(__float_as_int(x), 0x101F));
}
__device__ __forceinline__ float sum8(float x) {
    x += dpp_movf<0xB1>(x);
    x += dpp_movf<0x4E>(x);
    x += dpp_movf<0x141>(x);
    return x;
}
__device__ __forceinline__ float max8(float x) {
    x = fmaxf(x, dpp_movf<0xB1>(x));
    x = fmaxf(x, dpp_movf<0x4E>(x));
    x = fmaxf(x, dpp_movf<0x141>(x));
    return x;
}
// butterfly reduce-transpose over 8-lane group: p[j] holds partial for a=ig^j;
// returns full sum for a=ig.
__device__ __forceinline__ float reduce_xpose8(float p[8]) {
    p[0] += dpp_movf<0xB1>(p[1]);
    p[2] += dpp_movf<0xB1>(p[3]);
    p[4] += dpp_movf<0xB1>(p[5]);
    p[6] += dpp_movf<0xB1>(p[7]);
    p[0] += dpp_movf<0x4E>(p[2]);
    p[4] += dpp_movf<0x4E>(p[6]);
    p[0] += swz_xor4(p[4]);
    return p[0];
}

// ---------- merged prep: blocks [0,224) -> W bf16 repack; [224,480) -> x transpose ----------
__global__ __launch_bounds__(256)
void prep(const float* __restrict__ cw, const float* __restrict__ x,
          unsigned short* __restrict__ wp, unsigned short* __restrict__ xt) {
    __shared__ unsigned short tile[32 * 256];
    const int t = threadIdx.x;
    if (blockIdx.x < 224) {
        // W -> bf16, [s(7)][g(4)][oa(256)][j(8)], k = s*32+g*8+j
        const int idx = blockIdx.x * 256 + t;         // 57344 total
        const int j  = idx & 7;
        const int oa = (idx >> 3) & 255;
        const int g  = (idx >> 11) & 3;
        const int s  = idx >> 13;
        const int k  = s * 32 + g * 8 + j;
        wp[idx] = (k < 200) ? f2bf(cw[k * 256 + oa]) : (unsigned short)0;
        return;
    }
    // x -> bf16 transposed [b][y][x][i*8+ci]
    const int bid = blockIdx.x - 224;                 // 256 blocks
    const int b = bid >> 5, y = bid & 31;
    const float* src = x + (((size_t)((b << 8) + t)) << 10) + (y << 5);
    #pragma unroll
    for (int c = 0; c < 8; ++c) {
        float4 v = *(const float4*)(src + c * 4);
        tile[(c * 4 + 0) * 256 + t] = f2bf(v.x);
        tile[(c * 4 + 1) * 256 + t] = f2bf(v.y);
        tile[(c * 4 + 2) * 256 + t] = f2bf(v.z);
        tile[(c * 4 + 3) * 256 + t] = f2bf(v.w);
    }
    __syncthreads();
    unsigned short* dst = xt + ((size_t)bid << 13);
    #pragma unroll
    for (int c = 0; c < 4; ++c) {
        const int chunk = t + c * 256;
        *(short8*)(dst + chunk * 8) = *(const short8*)(&tile[chunk * 8]);
    }
}

// ---------- main fused kernel: 2 pixels / 512 threads / 8 waves ----------
__global__ __launch_bounds__(512, 4)
void capsule_mfma2(const unsigned short* __restrict__ xt,
                   const unsigned short* __restrict__ wp,
                   const float* __restrict__ conv_b,
                   const float* __restrict__ biases,
                   float* __restrict__ out)
{
    __shared__ __align__(16) char lds[39424];

    const int t   = threadIdx.x;
    const int blk = blockIdx.x;           // 4096
    const int b   = blk >> 9;
    const int rem = blk & 511;
    const int h   = rem >> 4;
    const int w0  = (rem & 15) << 1;      // pixels w0, w0+1

    // ---- stage patch: slot XOR-swizzled, row stride 512B ----
    for (int u = t; u < 960; u += 512) {
        const int i = u & 31, pos = u >> 5;          // pos in [0,30)
        const int ky = pos / 6, xl = pos - ky * 6;
        const int y = h + ky - 2, xx = w0 + xl - 2;
        short8 vv = {0, 0, 0, 0, 0, 0, 0, 0};
        if ((unsigned)y < 32u && (unsigned)xx < 32u)
            vv = *(const short8*)(xt + (((size_t)(((b << 5) + y) << 5) + xx) << 8) + i * 8);
        *(short8*)(lds + i * 512 + ((pos ^ (i & 15)) << 4)) = vv;
    }

    const int l  = t & 63, wv = t >> 6;   // 8 waves
    const int lm = l & 15, lg = l >> 4;   // conv C-layout coords
    const int o_l = l >> 3, ig = l & 7;   // routing coords
    const int o  = ((wv & 3) << 3) + o_l; // capsule 0..31
    const int q  = wv >> 2;               // pixel

    const float cb_own   = conv_b[t & 255];
    const float bias_own = biases[t & 255];

    // W s=0 prefetch (hides L2 latency under the staging barrier)
    const unsigned short* wbase = wp + lg * 2048 + ((((wv & 3) << 6) + lm) << 3);
    short8 a0[4];
    #pragma unroll
    for (int mt = 0; mt < 4; ++mt)
        a0[mt] = *(const short8*)(wbase + mt * 128);

    f32x4 acc[4][2];
    #pragma unroll
    for (int mt = 0; mt < 4; ++mt)
        #pragma unroll
        for (int ti = 0; ti < 2; ++ti)
            acc[mt][ti] = (f32x4){0.f, 0.f, 0.f, 0.f};

    __syncthreads();   // B0: patch ready

    // conv: M=oa (A=W, wave owns 64 oa), N=i (B=patch), K=224
    #pragma unroll
    for (int s = 0; s < 7; ++s) {
        short8 a[4];
        #pragma unroll
        for (int mt = 0; mt < 4; ++mt)
            a[mt] = (s == 0) ? a0[mt]
                             : *(const short8*)(wbase + s * 8192 + mt * 128);
        const int kt = s * 4 + lg;
        int pos = 0;
        if (kt <= 24) { const int ky = kt / 5; pos = ky * 6 + (kt - ky * 5); }
        const int pr = pos + q;           // logical slot; phys = pr ^ (i&15)
        const short8 b0 = *(const short8*)(lds + lm * 512 + ((pr ^ lm) << 4));
        const short8 b1 = *(const short8*)(lds + (16 + lm) * 512 + ((pr ^ lm) << 4));
        __builtin_amdgcn_s_setprio(1);
        #pragma unroll
        for (int mt = 0; mt < 4; ++mt) {
            acc[mt][0] = __builtin_amdgcn_mfma_f32_16x16x32_bf16(a[mt], b0, acc[mt][0], 0, 0, 0);
            acc[mt][1] = __builtin_amdgcn_mfma_f32_16x16x32_bf16(a[mt], b1, acc[mt][1], 0, 0, 0);
        }
        __builtin_amdgcn_s_setprio(0);
    }

    // ---- per-wave transpose, 4 rounds (mh,ro); vtr region dedicated ----
    // Hoisted addressing: write addresses identical across rounds ->
    //   m2=0 rows 4lg+r   : chunk0 = ((lm>>2)+(lg>>1))&3
    //   m2=1 rows 16+4lg+r: chunk  = chunk0^2
    float v[4][8];                        // v[di][j]: i = 4ig+di, a = ig^j
    char* vtrb = lds + 18944 + wv * 2560; // [32 rows][80 B]
    const int chunk0 = ((lm >> 2) + (lg >> 1)) & 3;
    char* wb0 = vtrb + (lg << 2) * 80 + (chunk0 << 4) + ((lm & 3) << 2);
    char* wb1 = vtrb + (16 + (lg << 2)) * 80 + ((chunk0 ^ 2) << 4) + ((lm & 3) << 2);
    const char* rb = vtrb + ((o_l & 3) << 3) * 80 + ((((ig & 3) + (o_l & 3)) & 3) << 4);
    #pragma unroll
    for (int mh = 0; mh < 2; ++mh)
        #pragma unroll
        for (int ro = 0; ro < 2; ++ro) {
            #pragma unroll
            for (int r = 0; r < 4; ++r) {
                *(float*)(wb0 + r * 80) = acc[mh * 2 + 0][ro][r];
                *(float*)(wb1 + r * 80) = acc[mh * 2 + 1][ro][r];
            }
            if ((ig >> 2) == ro && (o_l >> 2) == mh) {
                #pragma unroll
                for (int j = 0; j < 8; ++j) {
                    const f32x4 r4 = *(const f32x4*)(rb + (ig ^ j) * 80);
                    v[0][j] = r4[0]; v[1][j] = r4[1]; v[2][j] = r4[2]; v[3][j] = r4[3];
                }
            }
        }

    // routing arrays: [32 i][37] f32, stride 148 B (2-way max: banks 20*ig+o)
    float* logits_q = (float*)(lds + q * 4736);
    float* route_q  = (float*)(lds + 9472 + q * 4736);
    const int rw_byte = ig * 592 + o * 4;                // [i=4ig+di][o], +di*148
    const int sm_byte = o * 148 + (ig << 4);             // row i=o, cols 4ig.., b128

    float lacc[4] = {0.f, 0.f, 0.f, 0.f};
    float actv = 0.f;

    #pragma unroll
    for (int it = 0; it < 3; ++it) {
        // ---- preact: pre(o, a=ig) ----
        float pre;
        if (it == 0) {
            float p[8];
            #pragma unroll
            for (int j = 0; j < 8; ++j)
                p[j] = (v[0][j] + v[1][j]) + (v[2][j] + v[3][j]);
            const float R = reduce_xpose8(p);
            pre = fmaf(fmaf(cb_own, 32.f, R), 1.f / 33.f, bias_own);
        } else {
            float r4[4];
            #pragma unroll
            for (int di = 0; di < 4; ++di)
                r4[di] = *(const float*)((char*)route_q + rw_byte + di * 148);
            float p[8];
            #pragma unroll
            for (int j = 0; j < 8; ++j) {
                float s = v[0][j] * r4[0];
                s = fmaf(v[1][j], r4[1], s);
                s = fmaf(v[2][j], r4[2], s);
                s = fmaf(v[3][j], r4[3], s);
                p[j] = s;
            }
            const float S_o = sum8((r4[0] + r4[1]) + (r4[2] + r4[3]));
            const float P = reduce_xpose8(p);
            pre = fmaf(cb_own, S_o, P) + bias_own;
        }

        // ---- squash over atoms ----
        const float ns = sum8(pre * pre);
        actv = pre * ns * __builtin_amdgcn_rsqf(ns) * __builtin_amdgcn_rcpf(1.f + ns);

        if (it < 2) {
            // act allgather in xor-slot order
            float ag[8];
            ag[0] = actv;
            ag[4] = swz_xor4(ag[0]);
            ag[2] = dpp_movf<0x4E>(ag[0]);
            ag[6] = dpp_movf<0x4E>(ag[4]);
            ag[1] = dpp_movf<0xB1>(ag[0]);
            ag[3] = dpp_movf<0xB1>(ag[2]);
            ag[5] = dpp_movf<0xB1>(ag[4]);
            ag[7] = dpp_movf<0xB1>(ag[6]);
            const float cbact = sum8(cb_own * actv);

            // logit update in registers
            #pragma unroll
            for (int di = 0; di < 4; ++di) {
                float d = cbact;
                #pragma unroll
                for (int j = 0; j < 8; ++j)
                    d = fmaf(v[di][j], ag[j], d);
                lacc[di] += d;
            }

            // B1 (iter0 only): all conv patch reads done before logits reuse region
            if (it == 0) __syncthreads();

            #pragma unroll
            for (int di = 0; di < 4; ++di)
                *(float*)((char*)logits_q + rw_byte + di * 148) = lacc[di];
            __syncthreads();   // B2/B4

            // leaky softmax over o for row i = o
            f32x4 e = *(const f32x4*)((char*)logits_q + sm_byte);
            float mx = fmaxf(fmaxf(e[0], e[1]), fmaxf(e[2], e[3]));
            mx = max8(fmaxf(mx, 0.f));                   // include leak logit 0
            e[0] = __expf(e[0] - mx); e[1] = __expf(e[1] - mx);
            e[2] = __expf(e[2] - mx); e[3] = __expf(e[3] - mx);
            const float ssum = sum8((e[0] + e[1]) + (e[2] + e[3])) + __expf(-mx);
            const float inv = __builtin_amdgcn_rcpf(ssum);
            e[0] *= inv; e[1] *= inv; e[2] *= inv; e[3] *= inv;
            *(f32x4*)((char*)route_q + sm_byte) = e;
            __syncthreads();   // B3/B5
        }
    }

    // out[b][o][h][w][a]: a = ig
    const int pix = (h << 5) + w0 + q;
    out[(((size_t)(((b << 5) + o) << 10) + pix) << 3) + ig] = actv;
}

extern "C" void kernel_launch(void* const* d_in, const int* in_sizes, int n_in,
                              void* d_out, int out_size, void* d_ws, size_t ws_size,
                              hipStream_t stream) {
    const float* x      = (const float*)d_in[0];
    const float* conv_w = (const float*)d_in[1];
    const float* conv_b = (const float*)d_in[2];
    const float* biases = (const float*)d_in[3];
    unsigned short* wp = (unsigned short*)d_ws;                     // 114,688 B
    unsigned short* xt = (unsigned short*)((char*)d_ws + 131072);   // 4 MB
    prep<<<dim3(480), dim3(256), 0, stream>>>(conv_w, x, wp, xt);
    capsule_mfma2<<<dim3(4096), dim3(512), 0, stream>>>(xt, wp, conv_b, biases, (float*)d_out);
}